// Round 14
// baseline (159.696 us; speedup 1.0000x reference)
//
#include <hip/hip_runtime.h>
#include <math.h>

#define N_SUBN  50000
#define NE      500000
#define NB      5000
#define NL      (2*NB)    // nlist size (srci ++ dsti)
#define DDIM    100
#define TDIM    100
#define KATTR   200
#define NCHUNK  49        // ceil(N_SUBN/1024)

typedef __attribute__((ext_vector_type(8))) short short8;
typedef __attribute__((ext_vector_type(4))) float f32x4;

__device__ inline unsigned short f2bf(float f){
  union{float f; unsigned int u;} v; v.f = f;
  unsigned int r = (v.u + 0x7fffu + ((v.u >> 16) & 1u)) >> 16;   // RNE
  return (unsigned short)r;
}
__device__ inline float bf2f(unsigned short u){
  union{unsigned int u; float f;} v; v.u = ((unsigned int)u) << 16;
  return v.f;
}

// fast cos for |x| up to ~1e6: Cody-Waite 2-term reduction (fma-exact) + v_cos.
__device__ inline float fast_cos(float x){
  constexpr double TWO_PI_D = 6.2831853071795864769252867665590;
  constexpr float I2PI = (float)(1.0/TWO_PI_D);
  constexpr float C1 = (float)TWO_PI_D;
  constexpr float C2 = (float)(TWO_PI_D - (double)((float)TWO_PI_D));
  float k = rintf(x * I2PI);
  float r = fmaf(k, -C1, x);
  r = fmaf(k, -C2, r);
  return __cosf(r);
}

// ---- fused setup: zero cnt/mark/mark2 + lusub gather + pack Wnb (7 mats), Wqxcb (combined qex), Wfb, bcomb ----
__global__ __launch_bounds__(256) void k_misc(
    const int* __restrict__ lastu, const int* __restrict__ nid,
    int* __restrict__ cnt, int* __restrict__ mark, int* __restrict__ mark2,
    int* __restrict__ lusub,
    const float* __restrict__ We,
    const float* __restrict__ Wq, const float* __restrict__ Wk,
    const float* __restrict__ Wv, const float* __restrict__ Ws,
    const float* __restrict__ Wps, const float* __restrict__ Wpd,
    const float* __restrict__ Wpf, const float* __restrict__ bq,
    unsigned short* __restrict__ Wnb, unsigned short* __restrict__ Wqxcb,
    unsigned short* __restrict__ Wfb, float* __restrict__ bcomb)
{
  int i = blockIdx.x*256 + threadIdx.x;
  if (i < N_SUBN){
    cnt[i] = 0;
    mark[i] = 0;
    mark2[i] = 0;
    lusub[i] = lastu[nid[i]];
  }
  if (i < 7*28*64){           // 7 square GEMM weight matrices (K=100->128, N=100->112)
    int l = i & 63; int t = i >> 6;
    int which = t / 28; int t2 = t - which*28;
    int kt = t2 / 7; int nt = t2 - kt*7;
    const float* W = (which==0)?Wq:(which==1)?Wk:(which==2)?Wv:(which==3)?Ws:
                     (which==4)?Wps:(which==5)?Wpd:Wpf;
    int col = nt*16 + (l & 15);
    int kbase = kt*32 + ((l >> 4) << 3);
    short8 pack;
    #pragma unroll
    for (int j = 0; j < 8; ++j){
      int k = kbase + j;
      float v = (k < DDIM && col < DDIM) ? W[k*DDIM + col] : 0.f;
      pack[j] = (short)f2bf(v);
    }
    *((short8*)Wnb + i) = pack;
  }
  if (i < 4*25*64){           // combined qex GEMM: Bc[k][col(h,d)] = sum_j Wq[k][h50+j]*We[d][h50+j]
    int l = i & 63; int t = i >> 6;
    int kt = t / 25; int nt = t - kt*25;
    int col = nt*16 + (l & 15);          // 0..399
    int h = col / 200; int d = col - h*200;
    int kbase = kt*32 + ((l >> 4) << 3);
    short8 pack;
    #pragma unroll
    for (int j8 = 0; j8 < 8; ++j8){
      int k = kbase + j8;
      float v = 0.f;
      if (k < DDIM){
        const float* wqr = Wq + k*DDIM + h*50;
        const float* wer = We + d*DDIM + h*50;
        for (int j = 0; j < 50; ++j) v = fmaf(wqr[j], wer[j], v);
      }
      pack[j8] = (short)f2bf(v);
    }
    *((short8*)Wqxcb + i) = pack;
  }
  if (i < 400){               // bcomb[col] = sum_j bq[h50+j]*We[d][h50+j]
    int h = i / 200; int d = i - h*200;
    const float* wer = We + d*DDIM + h*50;
    const float* bqr = bq + h*50;
    float v = 0.f;
    for (int j = 0; j < 50; ++j) v = fmaf(bqr[j], wer[j], v);
    bcomb[i] = v;
  }
  if (i < 13*7*64){           // final GEMM: B[k][col] = (k/200==col/50)?We[k%200][col]:0
    int l = i & 63; int t = i >> 6;
    int kt = t / 7; int nt = t - kt*7;
    int col = nt*16 + (l & 15);
    int kbase = kt*32 + ((l >> 4) << 3);
    short8 pack;
    #pragma unroll
    for (int j = 0; j < 8; ++j){
      int k = kbase + j;
      float v = 0.f;
      if (col < DDIM && k < 2*KATTR){
        int h = col / 50; int blk = k / KATTR; int d = k - blk*KATTR;
        v = (blk == h) ? We[d*DDIM + col] : 0.f;
      }
      pack[j] = (short)f2bf(v);
    }
    *((short8*)Wfb + i) = pack;
  }
}

// ---- mark referenced nodes (separate launch: k_misc zeroes first) ----
__global__ void k_mark(const int* __restrict__ srci, const int* __restrict__ dsti,
                       int* __restrict__ mark){
  int i = blockIdx.x*blockDim.x + threadIdx.x;
  if (i < NB){
    mark[srci[i]] = 1;
    mark[dsti[i]] = 1;
  }
}

// ---------------- CSR: histogram over MARKED dst; also mark surviving sources ----------------
__global__ void k_hist(const int* __restrict__ ei, const int* __restrict__ mark,
                       int* __restrict__ cnt, int* __restrict__ mark2){
  int i = blockIdx.x*blockDim.x + threadIdx.x;
  if (i < NE){
    int d = ei[NE + i];
    if (mark[d]){
      atomicAdd(&cnt[d], 1);
      mark2[ei[i]] = 1;
    }
  }
}

// ---------------- CSR scan phase 1: per-1024-chunk sums ----------------
__global__ __launch_bounds__(256) void k_bsum(const int* __restrict__ cnt, int* __restrict__ bsum){
  __shared__ int wsum[4];
  int b = blockIdx.x, tid = threadIdx.x;
  int base = b*1024 + tid*4;
  int s = 0;
  #pragma unroll
  for (int i=0;i<4;i++){ int idx = base+i; if (idx < N_SUBN) s += cnt[idx]; }
  #pragma unroll
  for (int m=1;m<64;m<<=1) s += __shfl_xor(s, m);
  if ((tid&63)==0) wsum[tid>>6] = s;
  __syncthreads();
  if (tid==0) bsum[b] = wsum[0]+wsum[1]+wsum[2]+wsum[3];
}

// ---------------- CSR scan phase 2: per-chunk scan, inline chunk-prefix from bsum ----------------
__global__ __launch_bounds__(1024) void k_off(const int* __restrict__ cnt, const int* __restrict__ bsum,
                                              int* __restrict__ rowptr, int* __restrict__ ofs){
  __shared__ int sd[1024];
  __shared__ int sbb;
  int b = blockIdx.x, tid = threadIdx.x;
  if (tid < 64){
    int v = (tid < b) ? bsum[tid] : 0;   // b <= 48 < 64
    #pragma unroll
    for (int m=1;m<64;m<<=1) v += __shfl_xor(v, m);
    if (tid == 0) sbb = v;
  }
  int i = b*1024 + tid;
  int v = (i < N_SUBN) ? cnt[i] : 0;
  sd[tid] = v; __syncthreads();
  for (int off=1; off<1024; off<<=1){
    int t = (tid >= off) ? sd[tid-off] : 0;
    __syncthreads();
    sd[tid] += t;
    __syncthreads();
  }
  int incl = sd[tid] + sbb;
  if (i < N_SUBN){ rowptr[i+1] = incl; ofs[i] = incl - v; }
  if (i == 0) rowptr[0] = 0;
}

// ---- CSR bucket (MARKED dst only): ONE packed 16B record per edge ----
__global__ void k_perm(const int* __restrict__ ei, const int* __restrict__ tt,
                       const int* __restrict__ lusub, const int* __restrict__ mark,
                       int* __restrict__ ofs, uint4* __restrict__ spr){
  int i = blockIdx.x*blockDim.x + threadIdx.x;
  if (i < NE){
    int d = ei[NE + i];
    if (mark[d]){
      int s = ei[i];
      float rel = (float)(lusub[s] - tt[i]);
      int pos = atomicAdd(&ofs[d], 1);
      spr[pos] = make_uint4((unsigned)s, (unsigned)i, __float_as_uint(rel), 0u);
    }
  }
}

// ---------------- k,v for nodes that source a surviving edge (mark2) ----------------
__global__ __launch_bounds__(256, 4) void k_nodeKV(
    const float* __restrict__ mem, const int* __restrict__ nid,
    const int* __restrict__ mark2,
    const unsigned short* __restrict__ Wnb,
    const float* __restrict__ bk, const float* __restrict__ bv,
    unsigned short* __restrict__ kvb)
{
  const int tid = threadIdx.x;
  const int lane = tid & 63;
  const int w = tid >> 6;
  const int node0 = blockIdx.x*64;
  const int arow = w*16 + (lane & 15);
  const int koff = (lane >> 4) << 3;

  int node = node0 + arow;
  int nc = (node < N_SUBN) ? node : (N_SUBN-1);
  const bool need = (node < N_SUBN) && mark2[nc];
  const float* zrow = mem + (size_t)nid[nc]*DDIM;

  f32x4 ak[7], av[7];
  #pragma unroll
  for (int nt=0; nt<7; ++nt){ ak[nt] = (f32x4){0,0,0,0}; av[nt] = (f32x4){0,0,0,0}; }

  #pragma unroll
  for (int kt=0; kt<4; ++kt){
    const int k0 = kt*32 + koff;
    short8 a;
    #pragma unroll
    for (int j=0;j<8;++j) a[j] = 0;
    if (need){
      if (k0 + 7 < DDIM){
        float4 m0 = *(const float4*)(zrow + k0);
        float4 m1 = *(const float4*)(zrow + k0 + 4);
        a[0] = (short)f2bf(m0.x); a[1] = (short)f2bf(m0.y);
        a[2] = (short)f2bf(m0.z); a[3] = (short)f2bf(m0.w);
        a[4] = (short)f2bf(m1.x); a[5] = (short)f2bf(m1.y);
        a[6] = (short)f2bf(m1.z); a[7] = (short)f2bf(m1.w);
      } else if (k0 < DDIM){
        float4 m0 = *(const float4*)(zrow + 96);
        a[0] = (short)f2bf(m0.x); a[1] = (short)f2bf(m0.y);
        a[2] = (short)f2bf(m0.z); a[3] = (short)f2bf(m0.w);
      }
    }
    const short8* wk = (const short8*)Wnb + (size_t)((1*4 + kt)*7)*64 + lane;
    const short8* wv = (const short8*)Wnb + (size_t)((2*4 + kt)*7)*64 + lane;
    #pragma unroll
    for (int nt=0; nt<7; ++nt){
      ak[nt] = __builtin_amdgcn_mfma_f32_16x16x32_bf16(a, wk[(size_t)nt*64], ak[nt], 0, 0, 0);
      av[nt] = __builtin_amdgcn_mfma_f32_16x16x32_bf16(a, wv[(size_t)nt*64], av[nt], 0, 0, 0);
    }
  }

  const int colb = lane & 15;
  const int rbase = w*16 + ((lane >> 4) << 2);
  int nn0 = node0 + rbase;
  int m2[4];
  #pragma unroll
  for (int r=0; r<4; ++r){
    int nn = nn0 + r;
    m2[r] = (nn < N_SUBN) ? mark2[nn] : 0;
  }
  #pragma unroll
  for (int nt=0; nt<7; ++nt){
    int col = nt*16 + colb;
    if (col >= DDIM) continue;
    float bbk = bk[col], bbv = bv[col];
    #pragma unroll
    for (int r=0; r<4; ++r){
      if (m2[r]){
        int nn = nn0 + r;
        unsigned pk = (unsigned)f2bf(ak[nt][r] + bbk)
                    | ((unsigned)f2bf(av[nt][r] + bbv) << 16);
        *(unsigned*)(kvb + (size_t)nn*(2*DDIM) + col*2) = pk;
      }
    }
  }
}

// ---------------- fused q, skip, qex for nlist rows (z A-frags reused for all 3) ----------------
__global__ __launch_bounds__(256, 2) void k_nodeQSX(
    const float* __restrict__ mem, const int* __restrict__ nid,
    const int* __restrict__ srci, const int* __restrict__ dsti,
    const unsigned short* __restrict__ Wnb, const unsigned short* __restrict__ Wqxcb,
    const float* __restrict__ bq, const float* __restrict__ bs,
    const float* __restrict__ bcomb,
    float* __restrict__ qs, float* __restrict__ ss, unsigned short* __restrict__ qexb)
{
  const int tid = threadIdx.x;
  const int lane = tid & 63;
  const int w = tid >> 6;
  const int i0 = blockIdx.x*64;
  const int arow = w*16 + (lane & 15);
  const int koff = (lane >> 4) << 3;

  int idx = i0 + arow;
  int idxc = (idx < NL) ? idx : (NL-1);
  int node = (idxc < NB) ? srci[idxc] : dsti[idxc - NB];
  const float* zrow = mem + (size_t)nid[node]*DDIM;

  f32x4 aq[7], as_[7], ax[25];
  #pragma unroll
  for (int nt=0; nt<7; ++nt){ aq[nt] = (f32x4){0,0,0,0}; as_[nt] = (f32x4){0,0,0,0}; }
  #pragma unroll
  for (int nt=0; nt<25; ++nt) ax[nt] = (f32x4){0,0,0,0};

  #pragma unroll
  for (int kt=0; kt<4; ++kt){
    const int k0 = kt*32 + koff;
    short8 a;
    if (k0 + 7 < DDIM){
      float4 m0 = *(const float4*)(zrow + k0);
      float4 m1 = *(const float4*)(zrow + k0 + 4);
      a[0] = (short)f2bf(m0.x); a[1] = (short)f2bf(m0.y);
      a[2] = (short)f2bf(m0.z); a[3] = (short)f2bf(m0.w);
      a[4] = (short)f2bf(m1.x); a[5] = (short)f2bf(m1.y);
      a[6] = (short)f2bf(m1.z); a[7] = (short)f2bf(m1.w);
    } else if (k0 >= DDIM){
      #pragma unroll
      for (int j=0;j<8;++j) a[j] = 0;
    } else {
      float4 m0 = *(const float4*)(zrow + 96);
      a[0] = (short)f2bf(m0.x); a[1] = (short)f2bf(m0.y);
      a[2] = (short)f2bf(m0.z); a[3] = (short)f2bf(m0.w);
      a[4] = 0; a[5] = 0; a[6] = 0; a[7] = 0;
    }
    const short8* wq = (const short8*)Wnb + (size_t)((0*4 + kt)*7)*64 + lane;
    const short8* ws = (const short8*)Wnb + (size_t)((3*4 + kt)*7)*64 + lane;
    const short8* wx = (const short8*)Wqxcb + (size_t)(kt*25)*64 + lane;
    #pragma unroll
    for (int nt=0; nt<7; ++nt){
      aq[nt]  = __builtin_amdgcn_mfma_f32_16x16x32_bf16(a, wq[(size_t)nt*64], aq[nt], 0, 0, 0);
      as_[nt] = __builtin_amdgcn_mfma_f32_16x16x32_bf16(a, ws[(size_t)nt*64], as_[nt], 0, 0, 0);
    }
    #pragma unroll
    for (int nt=0; nt<25; ++nt)
      ax[nt] = __builtin_amdgcn_mfma_f32_16x16x32_bf16(a, wx[(size_t)nt*64], ax[nt], 0, 0, 0);
  }

  const int colb = lane & 15;
  const int rbase = w*16 + ((lane >> 4) << 2);
  int nd[4]; bool on[4];
  #pragma unroll
  for (int r=0; r<4; ++r){
    int ii = i0 + rbase + r;
    on[r] = ii < NL;
    int iic = on[r] ? ii : (NL-1);
    nd[r] = (iic < NB) ? srci[iic] : dsti[iic - NB];
  }
  #pragma unroll
  for (int nt=0; nt<7; ++nt){
    int col = nt*16 + colb;
    if (col >= DDIM) continue;
    float bbq = bq[col], bbs = bs[col];
    #pragma unroll
    for (int r=0; r<4; ++r){
      if (on[r]){
        qs[(size_t)nd[r]*DDIM + col] = aq[nt][r] + bbq;
        ss[(size_t)nd[r]*DDIM + col] = as_[nt][r] + bbs;
      }
    }
  }
  #pragma unroll
  for (int nt=0; nt<25; ++nt){
    int col = nt*16 + colb;   // 0..399
    float bc = bcomb[col];
    #pragma unroll
    for (int r=0; r<4; ++r){
      if (on[r]) qexb[(size_t)nd[r]*400 + col] = f2bf(ax[nt][r] + bc);
    }
  }
}

// ---------------- fused aggregation over nlist (R12 pipelined loop) ----------------
__global__ __launch_bounds__(256) void k_agg(
    const int* __restrict__ rowptr, const uint4* __restrict__ spr,
    const int* __restrict__ srci, const int* __restrict__ dsti,
    const float* __restrict__ msg, const float* __restrict__ qs,
    const unsigned short* __restrict__ qexb, const unsigned short* __restrict__ kvb,
    const float* __restrict__ wt, const float* __restrict__ bt,
    unsigned short* __restrict__ sbarb, float* __restrict__ numvb,
    float* __restrict__ denb)
{
  const int w = __builtin_amdgcn_readfirstlane(threadIdx.x >> 6);
  const int lane = threadIdx.x & 63;
  const int idx = blockIdx.x*4 + w;          // grid = NL/4 exactly
  const int node = (idx < NB) ? srci[idx] : dsti[idx - NB];
  const bool act = lane < 50;
  const int l = lane;
  const float INV = 0.14142135623730951f;   // 1/sqrt(50)

  float wtA=0,wtB=0,btA=0,btB=0,q0=0,q1=0;
  float qx0=0,qx1=0,qx2=0,qx3=0,qx4=0,qx5=0,qx6=0,qx7=0;
  if (act){
    wtA = wt[l]; wtB = wt[50+l]; btA = bt[l]; btB = bt[50+l];
    q0 = qs[(size_t)node*DDIM + l]; q1 = qs[(size_t)node*DDIM + 50 + l];
    const unsigned short* qe = qexb + (size_t)node*400;
    qx0 = bf2f(qe[l]);      qx1 = bf2f(qe[50+l]);
    qx2 = bf2f(qe[100+l]);  qx3 = bf2f(qe[150+l]);
    qx4 = bf2f(qe[200+l]);  qx5 = bf2f(qe[250+l]);
    qx6 = bf2f(qe[300+l]);  qx7 = bf2f(qe[350+l]);
  }
  const int b0 = rowptr[node], b1 = rowptr[node+1];
  float den0=0.f, den1=0.f, nv0=0.f, nv1=0.f;
  float sb0=0.f,sb1=0.f,sb2=0.f,sb3=0.f,sb4=0.f,sb5=0.f,sb6=0.f,sb7=0.f;

  const int nE = b1 - b0;
  const int npairs = nE >> 1;

  uint4 sA = make_uint4(0,0,0,0), sB = sA, nsA = sA, nsB = sA;
  float mAA=0,mBA=0,mAB=0,mBB=0;
  unsigned pA0=0,pA1=0,pB0=0,pB1=0;

  if (npairs > 0){
    sA = spr[b0]; sB = spr[b0+1];
    if (act){
      mAA = msg[(size_t)sA.y*DDIM + l];  mBA = msg[(size_t)sA.y*DDIM + 50 + l];
      mAB = msg[(size_t)sB.y*DDIM + l];  mBB = msg[(size_t)sB.y*DDIM + 50 + l];
      pA0 = *(const unsigned*)(kvb + (size_t)sA.x*(2*DDIM) + 2*l);
      pA1 = *(const unsigned*)(kvb + (size_t)sA.x*(2*DDIM) + 100 + 2*l);
      pB0 = *(const unsigned*)(kvb + (size_t)sB.x*(2*DDIM) + 2*l);
      pB1 = *(const unsigned*)(kvb + (size_t)sB.x*(2*DDIM) + 100 + 2*l);
    }
    if (npairs > 1){ nsA = spr[b0+2]; nsB = spr[b0+3]; }
  }

  for (int j = 0; j < npairs; ++j){
    float nmAA=0,nmBA=0,nmAB=0,nmBB=0;
    unsigned npA0=0,npA1=0,npB0=0,npB1=0;
    if (j+1 < npairs && act){
      nmAA = msg[(size_t)nsA.y*DDIM + l];  nmBA = msg[(size_t)nsA.y*DDIM + 50 + l];
      nmAB = msg[(size_t)nsB.y*DDIM + l];  nmBB = msg[(size_t)nsB.y*DDIM + 50 + l];
      npA0 = *(const unsigned*)(kvb + (size_t)nsA.x*(2*DDIM) + 2*l);
      npA1 = *(const unsigned*)(kvb + (size_t)nsA.x*(2*DDIM) + 100 + 2*l);
      npB0 = *(const unsigned*)(kvb + (size_t)nsB.x*(2*DDIM) + 2*l);
      npB1 = *(const unsigned*)(kvb + (size_t)nsB.x*(2*DDIM) + 100 + 2*l);
    }
    uint4 nnsA = nsA, nnsB = nsB;
    if (j+2 < npairs){
      nnsA = spr[b0 + 2*(j+2)];
      nnsB = spr[b0 + 2*(j+2) + 1];
    }

    float relA = __uint_as_float(sA.z);
    float relB = __uint_as_float(sB.z);
    float cAA=0,cBA=0,cAB=0,cBB=0;
    float kA0=0,vA0=0,kA1=0,vA1=0,kB0=0,vB0=0,kB1=0,vB1=0;
    if (act){
      kA0 = bf2f((unsigned short)(pA0 & 0xffff)); vA0 = bf2f((unsigned short)(pA0 >> 16));
      kA1 = bf2f((unsigned short)(pA1 & 0xffff)); vA1 = bf2f((unsigned short)(pA1 >> 16));
      kB0 = bf2f((unsigned short)(pB0 & 0xffff)); vB0 = bf2f((unsigned short)(pB0 >> 16));
      kB1 = bf2f((unsigned short)(pB1 & 0xffff)); vB1 = bf2f((unsigned short)(pB1 >> 16));
      cAA = fast_cos(__fadd_rn(__fmul_rn(relA, wtA), btA));
      cBA = fast_cos(__fadd_rn(__fmul_rn(relA, wtB), btB));
      cAB = fast_cos(__fadd_rn(__fmul_rn(relB, wtA), btA));
      cBB = fast_cos(__fadd_rn(__fmul_rn(relB, wtB), btB));
    }
    float pA_0 = fmaf(q0,kA0, fmaf(qx0,cAA, fmaf(qx1,cBA, fmaf(qx2,mAA, qx3*mBA))));
    float pA_1 = fmaf(q1,kA1, fmaf(qx4,cAA, fmaf(qx5,cBA, fmaf(qx6,mAA, qx7*mBA))));
    float pB_0 = fmaf(q0,kB0, fmaf(qx0,cAB, fmaf(qx1,cBB, fmaf(qx2,mAB, qx3*mBB))));
    float pB_1 = fmaf(q1,kB1, fmaf(qx4,cAB, fmaf(qx5,cBB, fmaf(qx6,mAB, qx7*mBB))));
    #pragma unroll
    for (int m=1; m<64; m<<=1){
      pA_0 += __shfl_xor(pA_0, m);
      pA_1 += __shfl_xor(pA_1, m);
      pB_0 += __shfl_xor(pB_0, m);
      pB_1 += __shfl_xor(pB_1, m);
    }
    float aA0 = __expf(pA_0*INV), aA1 = __expf(pA_1*INV);
    float aB0 = __expf(pB_0*INV), aB1 = __expf(pB_1*INV);
    den0 += aA0 + aB0; den1 += aA1 + aB1;
    nv0 = fmaf(aA0, vA0, nv0); nv0 = fmaf(aB0, vB0, nv0);
    nv1 = fmaf(aA1, vA1, nv1); nv1 = fmaf(aB1, vB1, nv1);
    sb0 = fmaf(aA0, cAA, sb0); sb0 = fmaf(aB0, cAB, sb0);
    sb1 = fmaf(aA0, cBA, sb1); sb1 = fmaf(aB0, cBB, sb1);
    sb2 = fmaf(aA0, mAA, sb2); sb2 = fmaf(aB0, mAB, sb2);
    sb3 = fmaf(aA0, mBA, sb3); sb3 = fmaf(aB0, mBB, sb3);
    sb4 = fmaf(aA1, cAA, sb4); sb4 = fmaf(aB1, cAB, sb4);
    sb5 = fmaf(aA1, cBA, sb5); sb5 = fmaf(aB1, cBB, sb5);
    sb6 = fmaf(aA1, mAA, sb6); sb6 = fmaf(aB1, mAB, sb6);
    sb7 = fmaf(aA1, mBA, sb7); sb7 = fmaf(aB1, mBB, sb7);

    sA = nsA; sB = nsB; nsA = nnsA; nsB = nnsB;
    mAA = nmAA; mBA = nmBA; mAB = nmAB; mBB = nmBB;
    pA0 = npA0; pA1 = npA1; pB0 = npB0; pB1 = npB1;
  }

  if (nE & 1){
    int p = b0 + 2*npairs;
    uint4 eA = spr[p];
    float relA = __uint_as_float(eA.z);
    float cAA=0,cBA=0,mA0=0,mB0=0,kA0=0,vA0=0,kA1=0,vA1=0;
    if (act){
      mA0 = msg[(size_t)eA.y*DDIM + l];  mB0 = msg[(size_t)eA.y*DDIM + 50 + l];
      unsigned tA0 = *(const unsigned*)(kvb + (size_t)eA.x*(2*DDIM) + 2*l);
      unsigned tA1 = *(const unsigned*)(kvb + (size_t)eA.x*(2*DDIM) + 100 + 2*l);
      kA0 = bf2f((unsigned short)(tA0 & 0xffff)); vA0 = bf2f((unsigned short)(tA0 >> 16));
      kA1 = bf2f((unsigned short)(tA1 & 0xffff)); vA1 = bf2f((unsigned short)(tA1 >> 16));
      cAA = fast_cos(__fadd_rn(__fmul_rn(relA, wtA), btA));
      cBA = fast_cos(__fadd_rn(__fmul_rn(relA, wtB), btB));
    }
    float pA_0 = fmaf(q0,kA0, fmaf(qx0,cAA, fmaf(qx1,cBA, fmaf(qx2,mA0, qx3*mB0))));
    float pA_1 = fmaf(q1,kA1, fmaf(qx4,cAA, fmaf(qx5,cBA, fmaf(qx6,mA0, qx7*mB0))));
    #pragma unroll
    for (int m=1; m<64; m<<=1){
      pA_0 += __shfl_xor(pA_0, m);
      pA_1 += __shfl_xor(pA_1, m);
    }
    float aA0 = __expf(pA_0*INV), aA1 = __expf(pA_1*INV);
    den0 += aA0; den1 += aA1;
    nv0 = fmaf(aA0, vA0, nv0);
    nv1 = fmaf(aA1, vA1, nv1);
    sb0 = fmaf(aA0, cAA, sb0); sb1 = fmaf(aA0, cBA, sb1);
    sb2 = fmaf(aA0, mA0, sb2); sb3 = fmaf(aA0, mB0, sb3);
    sb4 = fmaf(aA1, cAA, sb4); sb5 = fmaf(aA1, cBA, sb5);
    sb6 = fmaf(aA1, mA0, sb6); sb7 = fmaf(aA1, mB0, sb7);
  }

  if (act){
    unsigned short* sr = sbarb + (size_t)node*400;
    sr[l]       = f2bf(sb0); sr[50+l]  = f2bf(sb1);
    sr[100+l]   = f2bf(sb2); sr[150+l] = f2bf(sb3);
    sr[200+l]   = f2bf(sb4); sr[250+l] = f2bf(sb5);
    sr[300+l]   = f2bf(sb6); sr[350+l] = f2bf(sb7);
    numvb[(size_t)node*DDIM + l]      = nv0;
    numvb[(size_t)node*DDIM + 50 + l] = nv1;
  }
  if (lane == 0){
    denb[node*2]   = den0;
    denb[node*2+1] = den1;
  }
}

// ---------------- final over nlist: oute = (numv + sbar@We)/den + skip ----------------
__global__ __launch_bounds__(256) void k_final(
    const unsigned short* __restrict__ sbarb, const unsigned short* __restrict__ Wfb,
    const int* __restrict__ srci, const int* __restrict__ dsti,
    const float* __restrict__ numvb, const float* __restrict__ denb,
    const float* __restrict__ ssb, float* __restrict__ oute)
{
  const int tid = threadIdx.x;
  const int lane = tid & 63;
  const int w = tid >> 6;
  const int i0 = blockIdx.x*64;
  const int arow = w*16 + (lane & 15);
  const int koff = (lane >> 4) << 3;

  int idx = i0 + arow;
  int idxc = (idx < NL) ? idx : (NL-1);
  int node = (idxc < NB) ? srci[idxc] : dsti[idxc - NB];
  const unsigned short* srow = sbarb + (size_t)node*400;

  f32x4 acc[7];
  #pragma unroll
  for (int nt=0; nt<7; ++nt) acc[nt] = (f32x4){0,0,0,0};

  #pragma unroll
  for (int kt=0; kt<13; ++kt){
    const int k0 = kt*32 + koff;
    short8 a;
    if (k0 + 7 < 2*KATTR){
      a = *(const short8*)(srow + k0);
    } else {
      #pragma unroll
      for (int j=0;j<8;++j) a[j] = 0;
    }
    const short8* wb = (const short8*)Wfb + (size_t)(kt*7)*64 + lane;
    #pragma unroll
    for (int nt=0; nt<7; ++nt){
      short8 b = wb[(size_t)nt*64];
      acc[nt] = __builtin_amdgcn_mfma_f32_16x16x32_bf16(a, b, acc[nt], 0, 0, 0);
    }
  }

  const int colb = lane & 15;
  const int rbase = w*16 + ((lane >> 4) << 2);
  int nd[4]; bool on[4];
  #pragma unroll
  for (int r=0; r<4; ++r){
    int ii = i0 + rbase + r;
    on[r] = ii < NL;
    int iic = on[r] ? ii : (NL-1);
    nd[r] = (iic < NB) ? srci[iic] : dsti[iic - NB];
  }
  #pragma unroll
  for (int nt=0; nt<7; ++nt){
    int col = nt*16 + colb;
    if (col >= DDIM) continue;
    int h = col >= 50 ? 1 : 0;
    #pragma unroll
    for (int r=0; r<4; ++r){
      if (on[r]){
        float den = denb[nd[r]*2 + h];
        float nv  = numvb[(size_t)nd[r]*DDIM + col];
        oute[(size_t)nd[r]*DDIM + col] =
          (nv + acc[nt][r]) / (den + 1e-16f) + ssb[(size_t)nd[r]*DDIM + col];
      }
    }
  }
}

// ---------------- predictor via MFMA ----------------
__global__ __launch_bounds__(256) void k_pred(
    const float* __restrict__ oute, const int* __restrict__ srci, const int* __restrict__ dsti,
    const unsigned short* __restrict__ Wnb,
    const float* __restrict__ bps, const float* __restrict__ bpd,
    const float* __restrict__ bpf, float* __restrict__ outp)
{
  __shared__ float hl[64][104];
  const int tid = threadIdx.x;
  const int lane = tid & 63;
  const int w = tid >> 6;
  const int bb0 = blockIdx.x*64;
  const int arow = w*16 + (lane & 15);
  const int koff = (lane >> 4) << 3;

  int b = bb0 + arow;
  int bc = (b < NB) ? b : (NB-1);
  const float* srow = oute + (size_t)srci[bc]*DDIM;
  const float* drow = oute + (size_t)dsti[bc]*DDIM;

  f32x4 acc[7];
  #pragma unroll
  for (int nt=0; nt<7; ++nt) acc[nt] = (f32x4){0,0,0,0};

  #pragma unroll
  for (int kt=0; kt<4; ++kt){
    const int k0 = kt*32 + koff;
    short8 aS, aD;
    if (k0 + 7 < DDIM){
      float4 s0 = *(const float4*)(srow + k0);
      float4 s1 = *(const float4*)(srow + k0 + 4);
      float4 d0 = *(const float4*)(drow + k0);
      float4 d1 = *(const float4*)(drow + k0 + 4);
      aS[0]=(short)f2bf(s0.x); aS[1]=(short)f2bf(s0.y); aS[2]=(short)f2bf(s0.z); aS[3]=(short)f2bf(s0.w);
      aS[4]=(short)f2bf(s1.x); aS[5]=(short)f2bf(s1.y); aS[6]=(short)f2bf(s1.z); aS[7]=(short)f2bf(s1.w);
      aD[0]=(short)f2bf(d0.x); aD[1]=(short)f2bf(d0.y); aD[2]=(short)f2bf(d0.z); aD[3]=(short)f2bf(d0.w);
      aD[4]=(short)f2bf(d1.x); aD[5]=(short)f2bf(d1.y); aD[6]=(short)f2bf(d1.z); aD[7]=(short)f2bf(d1.w);
    } else if (k0 >= DDIM){
      #pragma unroll
      for (int j=0;j<8;++j){ aS[j]=0; aD[j]=0; }
    } else {
      float4 s0 = *(const float4*)(srow + 96);
      float4 d0 = *(const float4*)(drow + 96);
      aS[0]=(short)f2bf(s0.x); aS[1]=(short)f2bf(s0.y); aS[2]=(short)f2bf(s0.z); aS[3]=(short)f2bf(s0.w);
      aS[4]=0; aS[5]=0; aS[6]=0; aS[7]=0;
      aD[0]=(short)f2bf(d0.x); aD[1]=(short)f2bf(d0.y); aD[2]=(short)f2bf(d0.z); aD[3]=(short)f2bf(d0.w);
      aD[4]=0; aD[5]=0; aD[6]=0; aD[7]=0;
    }
    const short8* wps = (const short8*)Wnb + (size_t)((4*4 + kt)*7)*64 + lane;
    const short8* wpd = (const short8*)Wnb + (size_t)((5*4 + kt)*7)*64 + lane;
    #pragma unroll
    for (int nt=0; nt<7; ++nt){
      acc[nt] = __builtin_amdgcn_mfma_f32_16x16x32_bf16(aS, wps[(size_t)nt*64], acc[nt], 0, 0, 0);
      acc[nt] = __builtin_amdgcn_mfma_f32_16x16x32_bf16(aD, wpd[(size_t)nt*64], acc[nt], 0, 0, 0);
    }
  }

  const int colb = lane & 15;
  const int rbase = w*16 + ((lane >> 4) << 2);
  #pragma unroll
  for (int nt=0; nt<7; ++nt){
    int col = nt*16 + colb;
    if (col >= DDIM) continue;
    float bbias = bps[col] + bpd[col];
    #pragma unroll
    for (int r=0; r<4; ++r)
      hl[rbase + r][col] = fmaxf(acc[nt][r] + bbias, 0.f);
  }
  __syncthreads();

  f32x4 ac2[7];
  #pragma unroll
  for (int nt=0; nt<7; ++nt) ac2[nt] = (f32x4){0,0,0,0};

  #pragma unroll
  for (int kt=0; kt<4; ++kt){
    const int k0 = kt*32 + koff;
    short8 a;
    if (k0 + 7 < DDIM){
      float4 h0 = *(const float4*)(&hl[arow][k0]);
      float4 h1 = *(const float4*)(&hl[arow][k0 + 4]);
      a[0]=(short)f2bf(h0.x); a[1]=(short)f2bf(h0.y); a[2]=(short)f2bf(h0.z); a[3]=(short)f2bf(h0.w);
      a[4]=(short)f2bf(h1.x); a[5]=(short)f2bf(h1.y); a[6]=(short)f2bf(h1.z); a[7]=(short)f2bf(h1.w);
    } else if (k0 >= DDIM){
      #pragma unroll
      for (int j=0;j<8;++j) a[j] = 0;
    } else {
      float4 h0 = *(const float4*)(&hl[arow][96]);
      a[0]=(short)f2bf(h0.x); a[1]=(short)f2bf(h0.y); a[2]=(short)f2bf(h0.z); a[3]=(short)f2bf(h0.w);
      a[4]=0; a[5]=0; a[6]=0; a[7]=0;
    }
    const short8* wpf = (const short8*)Wnb + (size_t)((6*4 + kt)*7)*64 + lane;
    #pragma unroll
    for (int nt=0; nt<7; ++nt)
      ac2[nt] = __builtin_amdgcn_mfma_f32_16x16x32_bf16(a, wpf[(size_t)nt*64], ac2[nt], 0, 0, 0);
  }

  #pragma unroll
  for (int nt=0; nt<7; ++nt){
    int col = nt*16 + colb;
    if (col >= DDIM) continue;
    float bb = bpf[col];
    #pragma unroll
    for (int r=0; r<4; ++r){
      int bo = bb0 + rbase + r;
      if (bo < NB) outp[(size_t)bo*DDIM + col] = ac2[nt][r] + bb;
    }
  }
}

extern "C" void kernel_launch(void* const* d_in, const int* in_sizes, int n_in,
                              void* d_out, int out_size, void* d_ws, size_t ws_size,
                              hipStream_t stream)
{
  const float* mem   = (const float*)d_in[0];
  const int*   lastu = (const int*)  d_in[1];
  const int*   nid   = (const int*)  d_in[2];
  const int*   ei    = (const int*)  d_in[3];
  const int*   tt    = (const int*)  d_in[4];
  const float* msg   = (const float*)d_in[5];
  const int*   srci  = (const int*)  d_in[6];
  const int*   dsti  = (const int*)  d_in[7];
  const float* wtime = (const float*)d_in[8];
  const float* btime = (const float*)d_in[9];
  const float* Wq = (const float*)d_in[10]; const float* bq = (const float*)d_in[11];
  const float* Wk = (const float*)d_in[12]; const float* bk = (const float*)d_in[13];
  const float* Wv = (const float*)d_in[14]; const float* bv = (const float*)d_in[15];
  const float* We = (const float*)d_in[16];
  const float* Ws = (const float*)d_in[17]; const float* bs = (const float*)d_in[18];
  const float* Wps= (const float*)d_in[19]; const float* bps= (const float*)d_in[20];
  const float* Wpd= (const float*)d_in[21]; const float* bpd= (const float*)d_in[22];
  const float* Wpf= (const float*)d_in[23]; const float* bpf= (const float*)d_in[24];

  char* wsp = (char*)d_ws;
  auto alloc = [&](size_t bytes)->void*{
    void* p = (void*)wsp;
    wsp += (bytes + 255) & ~(size_t)255;
    return p;
  };
  float* qs   = (float*)alloc((size_t)N_SUBN*DDIM*4);
  unsigned short* kvb  = (unsigned short*)alloc((size_t)N_SUBN*DDIM*2*2);
  float* ssb  = (float*)alloc((size_t)N_SUBN*DDIM*4);
  float* oute = (float*)alloc((size_t)N_SUBN*DDIM*4);
  unsigned short* qexb = (unsigned short*)alloc((size_t)N_SUBN*400*2);
  unsigned short* sbarb= (unsigned short*)alloc((size_t)N_SUBN*400*2);
  float* numvb= (float*)alloc((size_t)N_SUBN*DDIM*4);
  float* denb = (float*)alloc((size_t)N_SUBN*2*4);
  int* cnt    = (int*)alloc((size_t)N_SUBN*4);
  int* mark   = (int*)alloc((size_t)N_SUBN*4);
  int* mark2  = (int*)alloc((size_t)N_SUBN*4);
  int* rowptr = (int*)alloc((size_t)(N_SUBN+1)*4);
  int* ofs    = (int*)alloc((size_t)N_SUBN*4);
  int* bsum   = (int*)alloc((size_t)NCHUNK*4);
  uint4* spr  = (uint4*)alloc((size_t)NE*16);
  int* lusub  = (int*)alloc((size_t)N_SUBN*4);
  unsigned short* Wnb   = (unsigned short*)alloc((size_t)7*28*64*8*2);
  unsigned short* Wqxcb = (unsigned short*)alloc((size_t)4*25*64*8*2);
  unsigned short* Wfb   = (unsigned short*)alloc((size_t)13*7*64*8*2);
  float* bcomb = (float*)alloc((size_t)400*4);

  k_misc<<<(N_SUBN+255)/256, 256, 0, stream>>>(lastu, nid, cnt, mark, mark2, lusub, We,
                                               Wq, Wk, Wv, Ws, Wps, Wpd, Wpf, bq,
                                               Wnb, Wqxcb, Wfb, bcomb);
  k_mark<<<(NB+255)/256, 256, 0, stream>>>(srci, dsti, mark);
  k_hist<<<(NE+255)/256, 256, 0, stream>>>(ei, mark, cnt, mark2);
  k_bsum<<<NCHUNK, 256, 0, stream>>>(cnt, bsum);
  k_off<<<NCHUNK, 1024, 0, stream>>>(cnt, bsum, rowptr, ofs);
  k_perm<<<(NE+255)/256, 256, 0, stream>>>(ei, tt, lusub, mark, ofs, spr);

  k_nodeKV<<<(N_SUBN+63)/64, 256, 0, stream>>>(mem, nid, mark2, Wnb, bk, bv, kvb);
  k_nodeQSX<<<(NL+63)/64, 256, 0, stream>>>(mem, nid, srci, dsti, Wnb, Wqxcb,
                                            bq, bs, bcomb, qs, ssb, qexb);

  k_agg<<<NL/4, 256, 0, stream>>>(rowptr, spr, srci, dsti, msg, qs,
                                  qexb, kvb, wtime, btime,
                                  sbarb, numvb, denb);

  k_final<<<(NL+63)/64, 256, 0, stream>>>(sbarb, Wfb, srci, dsti, numvb, denb, ssb, oute);

  k_pred<<<(NB+63)/64, 256, 0, stream>>>(oute, srci, dsti, Wnb, bps, bpd, bpf,
                                         (float*)d_out);
}

// Round 15
// 144.657 us; speedup vs baseline: 1.1040x; 1.1040x over previous
//
#include <hip/hip_runtime.h>
#include <math.h>

#define N_SUBN  50000
#define NE      500000
#define NB      5000
#define NL      (2*NB)    // nlist size (srci ++ dsti)
#define DDIM    100
#define TDIM    100
#define KATTR   200
#define NCHUNK  49        // ceil(N_SUBN/1024)

typedef __attribute__((ext_vector_type(8))) short short8;
typedef __attribute__((ext_vector_type(4))) float f32x4;

__device__ inline unsigned short f2bf(float f){
  union{float f; unsigned int u;} v; v.f = f;
  unsigned int r = (v.u + 0x7fffu + ((v.u >> 16) & 1u)) >> 16;   // RNE
  return (unsigned short)r;
}
__device__ inline float bf2f(unsigned short u){
  union{unsigned int u; float f;} v; v.u = ((unsigned int)u) << 16;
  return v.f;
}

// fast cos for |x| up to ~1e6: Cody-Waite 2-term reduction (fma-exact) + v_cos.
__device__ inline float fast_cos(float x){
  constexpr double TWO_PI_D = 6.2831853071795864769252867665590;
  constexpr float I2PI = (float)(1.0/TWO_PI_D);
  constexpr float C1 = (float)TWO_PI_D;
  constexpr float C2 = (float)(TWO_PI_D - (double)((float)TWO_PI_D));
  float k = rintf(x * I2PI);
  float r = fmaf(k, -C1, x);
  r = fmaf(k, -C2, r);
  return __cosf(r);
}

// ---- fused setup: zero cnt/mark/mark2 + lusub gather + pack Wnb (7 mats), Wqxb, Wfb ----
__global__ __launch_bounds__(256) void k_misc(
    const int* __restrict__ lastu, const int* __restrict__ nid,
    int* __restrict__ cnt, int* __restrict__ mark, int* __restrict__ mark2,
    int* __restrict__ lusub,
    const float* __restrict__ We,
    const float* __restrict__ Wq, const float* __restrict__ Wk,
    const float* __restrict__ Wv, const float* __restrict__ Ws,
    const float* __restrict__ Wps, const float* __restrict__ Wpd,
    const float* __restrict__ Wpf,
    unsigned short* __restrict__ Wnb, unsigned short* __restrict__ Wqxb,
    unsigned short* __restrict__ Wfb)
{
  int i = blockIdx.x*256 + threadIdx.x;
  if (i < N_SUBN){
    cnt[i] = 0;
    mark[i] = 0;
    mark2[i] = 0;
    lusub[i] = lastu[nid[i]];
  }
  if (i < 7*28*64){           // 7 square GEMM weight matrices (K=100->128, N=100->112)
    int l = i & 63; int t = i >> 6;
    int which = t / 28; int t2 = t - which*28;
    int kt = t2 / 7; int nt = t2 - kt*7;
    const float* W = (which==0)?Wq:(which==1)?Wk:(which==2)?Wv:(which==3)?Ws:
                     (which==4)?Wps:(which==5)?Wpd:Wpf;
    int col = nt*16 + (l & 15);
    int kbase = kt*32 + ((l >> 4) << 3);
    short8 pack;
    #pragma unroll
    for (int j = 0; j < 8; ++j){
      int k = kbase + j;
      float v = (k < DDIM && col < DDIM) ? W[k*DDIM + col] : 0.f;
      pack[j] = (short)f2bf(v);
    }
    *((short8*)Wnb + i) = pack;
  }
  if (i < 4*25*64){           // qex GEMM: B[k][col] = (h*50<=k<h*50+50)?We[d][k]:0
    int l = i & 63; int t = i >> 6;
    int kt = t / 25; int nt = t - kt*25;
    int col = nt*16 + (l & 15);          // 0..399
    int h = col / 200; int d = col - h*200;
    int kbase = kt*32 + ((l >> 4) << 3);
    short8 pack;
    #pragma unroll
    for (int j = 0; j < 8; ++j){
      int k = kbase + j;
      float v = (k >= h*50 && k < h*50 + 50) ? We[d*DDIM + k] : 0.f;
      pack[j] = (short)f2bf(v);
    }
    *((short8*)Wqxb + i) = pack;
  }
  if (i < 13*7*64){           // final GEMM: B[k][col] = (k/200==col/50)?We[k%200][col]:0
    int l = i & 63; int t = i >> 6;
    int kt = t / 7; int nt = t - kt*7;
    int col = nt*16 + (l & 15);
    int kbase = kt*32 + ((l >> 4) << 3);
    short8 pack;
    #pragma unroll
    for (int j = 0; j < 8; ++j){
      int k = kbase + j;
      float v = 0.f;
      if (col < DDIM && k < 2*KATTR){
        int h = col / 50; int blk = k / KATTR; int d = k - blk*KATTR;
        v = (blk == h) ? We[d*DDIM + col] : 0.f;
      }
      pack[j] = (short)f2bf(v);
    }
    *((short8*)Wfb + i) = pack;
  }
}

// ---- mark referenced nodes (race-benign: all write 1) ----
__global__ void k_mark(const int* __restrict__ srci, const int* __restrict__ dsti,
                       int* __restrict__ mark){
  int i = blockIdx.x*blockDim.x + threadIdx.x;
  if (i < NB){
    mark[srci[i]] = 1;
    mark[dsti[i]] = 1;
  }
}

// ---------------- CSR: histogram over MARKED dst; also mark surviving sources ----------------
__global__ void k_hist(const int* __restrict__ ei, const int* __restrict__ mark,
                       int* __restrict__ cnt, int* __restrict__ mark2){
  int i = blockIdx.x*blockDim.x + threadIdx.x;
  if (i < NE){
    int d = ei[NE + i];
    if (mark[d]){
      atomicAdd(&cnt[d], 1);
      mark2[ei[i]] = 1;
    }
  }
}

// ---------------- CSR scan phase 1: per-1024-chunk sums ----------------
__global__ __launch_bounds__(256) void k_bsum(const int* __restrict__ cnt, int* __restrict__ bsum){
  __shared__ int wsum[4];
  int b = blockIdx.x, tid = threadIdx.x;
  int base = b*1024 + tid*4;
  int s = 0;
  #pragma unroll
  for (int i=0;i<4;i++){ int idx = base+i; if (idx < N_SUBN) s += cnt[idx]; }
  #pragma unroll
  for (int m=1;m<64;m<<=1) s += __shfl_xor(s, m);
  if ((tid&63)==0) wsum[tid>>6] = s;
  __syncthreads();
  if (tid==0) bsum[b] = wsum[0]+wsum[1]+wsum[2]+wsum[3];
}

// ---------------- CSR scan phase 2: per-chunk scan, inline chunk-prefix from bsum ----------------
__global__ __launch_bounds__(1024) void k_off(const int* __restrict__ cnt, const int* __restrict__ bsum,
                                              int* __restrict__ rowptr, int* __restrict__ ofs){
  __shared__ int sd[1024];
  __shared__ int sbb;
  int b = blockIdx.x, tid = threadIdx.x;
  if (tid < 64){
    int v = (tid < b) ? bsum[tid] : 0;   // b <= 48 < 64
    #pragma unroll
    for (int m=1;m<64;m<<=1) v += __shfl_xor(v, m);
    if (tid == 0) sbb = v;
  }
  int i = b*1024 + tid;
  int v = (i < N_SUBN) ? cnt[i] : 0;
  sd[tid] = v; __syncthreads();
  for (int off=1; off<1024; off<<=1){
    int t = (tid >= off) ? sd[tid-off] : 0;
    __syncthreads();
    sd[tid] += t;
    __syncthreads();
  }
  int incl = sd[tid] + sbb;
  if (i < N_SUBN){ rowptr[i+1] = incl; ofs[i] = incl - v; }
  if (i == 0) rowptr[0] = 0;
}

// ---- CSR bucket (MARKED dst only): ONE packed 16B record per edge ----
__global__ void k_perm(const int* __restrict__ ei, const int* __restrict__ tt,
                       const int* __restrict__ lusub, const int* __restrict__ mark,
                       int* __restrict__ ofs, uint4* __restrict__ spr){
  int i = blockIdx.x*blockDim.x + threadIdx.x;
  if (i < NE){
    int d = ei[NE + i];
    if (mark[d]){
      int s = ei[i];
      float rel = (float)(lusub[s] - tt[i]);
      int pos = atomicAdd(&ofs[d], 1);
      spr[pos] = make_uint4((unsigned)s, (unsigned)i, __float_as_uint(rel), 0u);
    }
  }
}

// ---------------- k,v for nodes that source a surviving edge (mark2) ----------------
__global__ __launch_bounds__(256, 4) void k_nodeKV(
    const float* __restrict__ mem, const int* __restrict__ nid,
    const int* __restrict__ mark2,
    const unsigned short* __restrict__ Wnb,
    const float* __restrict__ bk, const float* __restrict__ bv,
    unsigned short* __restrict__ kvb)
{
  const int tid = threadIdx.x;
  const int lane = tid & 63;
  const int w = tid >> 6;
  const int node0 = blockIdx.x*64;
  const int arow = w*16 + (lane & 15);
  const int koff = (lane >> 4) << 3;

  int node = node0 + arow;
  int nc = (node < N_SUBN) ? node : (N_SUBN-1);
  const bool need = (node < N_SUBN) && mark2[nc];
  const float* zrow = mem + (size_t)nid[nc]*DDIM;

  f32x4 ak[7], av[7];
  #pragma unroll
  for (int nt=0; nt<7; ++nt){ ak[nt] = (f32x4){0,0,0,0}; av[nt] = (f32x4){0,0,0,0}; }

  #pragma unroll
  for (int kt=0; kt<4; ++kt){
    const int k0 = kt*32 + koff;
    short8 a;
    #pragma unroll
    for (int j=0;j<8;++j) a[j] = 0;
    if (need){
      if (k0 + 7 < DDIM){
        float4 m0 = *(const float4*)(zrow + k0);
        float4 m1 = *(const float4*)(zrow + k0 + 4);
        a[0] = (short)f2bf(m0.x); a[1] = (short)f2bf(m0.y);
        a[2] = (short)f2bf(m0.z); a[3] = (short)f2bf(m0.w);
        a[4] = (short)f2bf(m1.x); a[5] = (short)f2bf(m1.y);
        a[6] = (short)f2bf(m1.z); a[7] = (short)f2bf(m1.w);
      } else if (k0 < DDIM){
        float4 m0 = *(const float4*)(zrow + 96);
        a[0] = (short)f2bf(m0.x); a[1] = (short)f2bf(m0.y);
        a[2] = (short)f2bf(m0.z); a[3] = (short)f2bf(m0.w);
      }
    }
    const short8* wk = (const short8*)Wnb + (size_t)((1*4 + kt)*7)*64 + lane;
    const short8* wv = (const short8*)Wnb + (size_t)((2*4 + kt)*7)*64 + lane;
    #pragma unroll
    for (int nt=0; nt<7; ++nt){
      ak[nt] = __builtin_amdgcn_mfma_f32_16x16x32_bf16(a, wk[(size_t)nt*64], ak[nt], 0, 0, 0);
      av[nt] = __builtin_amdgcn_mfma_f32_16x16x32_bf16(a, wv[(size_t)nt*64], av[nt], 0, 0, 0);
    }
  }

  const int colb = lane & 15;
  const int rbase = w*16 + ((lane >> 4) << 2);
  int nn0 = node0 + rbase;
  int m2[4];
  #pragma unroll
  for (int r=0; r<4; ++r){
    int nn = nn0 + r;
    m2[r] = (nn < N_SUBN) ? mark2[nn] : 0;
  }
  #pragma unroll
  for (int nt=0; nt<7; ++nt){
    int col = nt*16 + colb;
    if (col >= DDIM) continue;
    float bbk = bk[col], bbv = bv[col];
    #pragma unroll
    for (int r=0; r<4; ++r){
      if (m2[r]){
        int nn = nn0 + r;
        unsigned pk = (unsigned)f2bf(ak[nt][r] + bbk)
                    | ((unsigned)f2bf(av[nt][r] + bbv) << 16);
        *(unsigned*)(kvb + (size_t)nn*(2*DDIM) + col*2) = pk;
      }
    }
  }
}

// ---------------- q,skip for REFERENCED nodes only (nlist = srci ++ dsti) ----------------
__global__ __launch_bounds__(256, 4) void k_nodeQS(
    const float* __restrict__ mem, const int* __restrict__ nid,
    const int* __restrict__ srci, const int* __restrict__ dsti,
    const unsigned short* __restrict__ Wnb,
    const float* __restrict__ bq, const float* __restrict__ bs,
    float* __restrict__ qs, float* __restrict__ ss)
{
  const int tid = threadIdx.x;
  const int lane = tid & 63;
  const int w = tid >> 6;
  const int i0 = blockIdx.x*64;
  const int arow = w*16 + (lane & 15);
  const int koff = (lane >> 4) << 3;

  int idx = i0 + arow;
  int idxc = (idx < NL) ? idx : (NL-1);
  int node = (idxc < NB) ? srci[idxc] : dsti[idxc - NB];
  const float* zrow = mem + (size_t)nid[node]*DDIM;

  f32x4 aq[7], as_[7];
  #pragma unroll
  for (int nt=0; nt<7; ++nt){ aq[nt] = (f32x4){0,0,0,0}; as_[nt] = (f32x4){0,0,0,0}; }

  #pragma unroll
  for (int kt=0; kt<4; ++kt){
    const int k0 = kt*32 + koff;
    short8 a;
    if (k0 + 7 < DDIM){
      float4 m0 = *(const float4*)(zrow + k0);
      float4 m1 = *(const float4*)(zrow + k0 + 4);
      a[0] = (short)f2bf(m0.x); a[1] = (short)f2bf(m0.y);
      a[2] = (short)f2bf(m0.z); a[3] = (short)f2bf(m0.w);
      a[4] = (short)f2bf(m1.x); a[5] = (short)f2bf(m1.y);
      a[6] = (short)f2bf(m1.z); a[7] = (short)f2bf(m1.w);
    } else if (k0 >= DDIM){
      #pragma unroll
      for (int j=0;j<8;++j) a[j] = 0;
    } else {
      float4 m0 = *(const float4*)(zrow + 96);
      a[0] = (short)f2bf(m0.x); a[1] = (short)f2bf(m0.y);
      a[2] = (short)f2bf(m0.z); a[3] = (short)f2bf(m0.w);
      a[4] = 0; a[5] = 0; a[6] = 0; a[7] = 0;
    }
    const short8* wq = (const short8*)Wnb + (size_t)((0*4 + kt)*7)*64 + lane;
    const short8* ws = (const short8*)Wnb + (size_t)((3*4 + kt)*7)*64 + lane;
    #pragma unroll
    for (int nt=0; nt<7; ++nt){
      aq[nt]  = __builtin_amdgcn_mfma_f32_16x16x32_bf16(a, wq[(size_t)nt*64], aq[nt], 0, 0, 0);
      as_[nt] = __builtin_amdgcn_mfma_f32_16x16x32_bf16(a, ws[(size_t)nt*64], as_[nt], 0, 0, 0);
    }
  }

  const int colb = lane & 15;
  const int rbase = w*16 + ((lane >> 4) << 2);
  int nd[4]; bool on[4];
  #pragma unroll
  for (int r=0; r<4; ++r){
    int ii = i0 + rbase + r;
    on[r] = ii < NL;
    int iic = on[r] ? ii : (NL-1);
    nd[r] = (iic < NB) ? srci[iic] : dsti[iic - NB];
  }
  #pragma unroll
  for (int nt=0; nt<7; ++nt){
    int col = nt*16 + colb;
    if (col >= DDIM) continue;
    float bbq = bq[col], bbs = bs[col];
    #pragma unroll
    for (int r=0; r<4; ++r){
      if (on[r]){
        qs[(size_t)nd[r]*DDIM + col] = aq[nt][r] + bbq;
        ss[(size_t)nd[r]*DDIM + col] = as_[nt][r] + bbs;
      }
    }
  }
}

// ---------------- qex GEMM over nlist ----------------
__global__ __launch_bounds__(256) void k_qex(
    const float* __restrict__ qs, const int* __restrict__ srci, const int* __restrict__ dsti,
    const unsigned short* __restrict__ Wqxb, unsigned short* __restrict__ qexb)
{
  const int tid = threadIdx.x;
  const int lane = tid & 63;
  const int w = tid >> 6;
  const int i0 = blockIdx.x*64;
  const int arow = w*16 + (lane & 15);
  const int koff = (lane >> 4) << 3;

  int idx = i0 + arow;
  int idxc = (idx < NL) ? idx : (NL-1);
  int node = (idxc < NB) ? srci[idxc] : dsti[idxc - NB];
  const float* qrow = qs + (size_t)node*DDIM;

  f32x4 acc[25];
  #pragma unroll
  for (int nt=0; nt<25; ++nt) acc[nt] = (f32x4){0,0,0,0};

  #pragma unroll
  for (int kt=0; kt<4; ++kt){
    const int k0 = kt*32 + koff;
    short8 a;
    if (k0 + 7 < DDIM){
      float4 m0 = *(const float4*)(qrow + k0);
      float4 m1 = *(const float4*)(qrow + k0 + 4);
      a[0] = (short)f2bf(m0.x); a[1] = (short)f2bf(m0.y);
      a[2] = (short)f2bf(m0.z); a[3] = (short)f2bf(m0.w);
      a[4] = (short)f2bf(m1.x); a[5] = (short)f2bf(m1.y);
      a[6] = (short)f2bf(m1.z); a[7] = (short)f2bf(m1.w);
    } else if (k0 >= DDIM){
      #pragma unroll
      for (int j=0;j<8;++j) a[j] = 0;
    } else {
      float4 m0 = *(const float4*)(qrow + 96);
      a[0] = (short)f2bf(m0.x); a[1] = (short)f2bf(m0.y);
      a[2] = (short)f2bf(m0.z); a[3] = (short)f2bf(m0.w);
      a[4] = 0; a[5] = 0; a[6] = 0; a[7] = 0;
    }
    const short8* wb = (const short8*)Wqxb + (size_t)(kt*25)*64 + lane;
    #pragma unroll
    for (int nt=0; nt<25; ++nt){
      short8 b = wb[(size_t)nt*64];
      acc[nt] = __builtin_amdgcn_mfma_f32_16x16x32_bf16(a, b, acc[nt], 0, 0, 0);
    }
  }

  const int colb = lane & 15;
  const int rbase = w*16 + ((lane >> 4) << 2);
  int nd[4]; bool on[4];
  #pragma unroll
  for (int r=0; r<4; ++r){
    int ii = i0 + rbase + r;
    on[r] = ii < NL;
    int iic = on[r] ? ii : (NL-1);
    nd[r] = (iic < NB) ? srci[iic] : dsti[iic - NB];
  }
  #pragma unroll
  for (int nt=0; nt<25; ++nt){
    int col = nt*16 + colb;
    #pragma unroll
    for (int r=0; r<4; ++r){
      if (on[r]) qexb[(size_t)nd[r]*400 + col] = f2bf(acc[nt][r]);
    }
  }
}

// ---------------- fused aggregation over nlist (R12 pipelined loop) ----------------
__global__ __launch_bounds__(256) void k_agg(
    const int* __restrict__ rowptr, const uint4* __restrict__ spr,
    const int* __restrict__ srci, const int* __restrict__ dsti,
    const float* __restrict__ msg, const float* __restrict__ qs,
    const unsigned short* __restrict__ qexb, const unsigned short* __restrict__ kvb,
    const float* __restrict__ wt, const float* __restrict__ bt,
    unsigned short* __restrict__ sbarb, float* __restrict__ numvb,
    float* __restrict__ denb)
{
  const int w = __builtin_amdgcn_readfirstlane(threadIdx.x >> 6);
  const int lane = threadIdx.x & 63;
  const int idx = blockIdx.x*4 + w;          // grid = NL/4 exactly
  const int node = (idx < NB) ? srci[idx] : dsti[idx - NB];
  const bool act = lane < 50;
  const int l = lane;
  const float INV = 0.14142135623730951f;   // 1/sqrt(50)

  float wtA=0,wtB=0,btA=0,btB=0,q0=0,q1=0;
  float qx0=0,qx1=0,qx2=0,qx3=0,qx4=0,qx5=0,qx6=0,qx7=0;
  if (act){
    wtA = wt[l]; wtB = wt[50+l]; btA = bt[l]; btB = bt[50+l];
    q0 = qs[(size_t)node*DDIM + l]; q1 = qs[(size_t)node*DDIM + 50 + l];
    const unsigned short* qe = qexb + (size_t)node*400;
    qx0 = bf2f(qe[l]);      qx1 = bf2f(qe[50+l]);
    qx2 = bf2f(qe[100+l]);  qx3 = bf2f(qe[150+l]);
    qx4 = bf2f(qe[200+l]);  qx5 = bf2f(qe[250+l]);
    qx6 = bf2f(qe[300+l]);  qx7 = bf2f(qe[350+l]);
  }
  const int b0 = rowptr[node], b1 = rowptr[node+1];
  float den0=0.f, den1=0.f, nv0=0.f, nv1=0.f;
  float sb0=0.f,sb1=0.f,sb2=0.f,sb3=0.f,sb4=0.f,sb5=0.f,sb6=0.f,sb7=0.f;

  const int nE = b1 - b0;
  const int npairs = nE >> 1;

  uint4 sA = make_uint4(0,0,0,0), sB = sA, nsA = sA, nsB = sA;
  float mAA=0,mBA=0,mAB=0,mBB=0;
  unsigned pA0=0,pA1=0,pB0=0,pB1=0;

  if (npairs > 0){
    sA = spr[b0]; sB = spr[b0+1];
    if (act){
      mAA = msg[(size_t)sA.y*DDIM + l];  mBA = msg[(size_t)sA.y*DDIM + 50 + l];
      mAB = msg[(size_t)sB.y*DDIM + l];  mBB = msg[(size_t)sB.y*DDIM + 50 + l];
      pA0 = *(const unsigned*)(kvb + (size_t)sA.x*(2*DDIM) + 2*l);
      pA1 = *(const unsigned*)(kvb + (size_t)sA.x*(2*DDIM) + 100 + 2*l);
      pB0 = *(const unsigned*)(kvb + (size_t)sB.x*(2*DDIM) + 2*l);
      pB1 = *(const unsigned*)(kvb + (size_t)sB.x*(2*DDIM) + 100 + 2*l);
    }
    if (npairs > 1){ nsA = spr[b0+2]; nsB = spr[b0+3]; }
  }

  for (int j = 0; j < npairs; ++j){
    float nmAA=0,nmBA=0,nmAB=0,nmBB=0;
    unsigned npA0=0,npA1=0,npB0=0,npB1=0;
    if (j+1 < npairs && act){
      nmAA = msg[(size_t)nsA.y*DDIM + l];  nmBA = msg[(size_t)nsA.y*DDIM + 50 + l];
      nmAB = msg[(size_t)nsB.y*DDIM + l];  nmBB = msg[(size_t)nsB.y*DDIM + 50 + l];
      npA0 = *(const unsigned*)(kvb + (size_t)nsA.x*(2*DDIM) + 2*l);
      npA1 = *(const unsigned*)(kvb + (size_t)nsA.x*(2*DDIM) + 100 + 2*l);
      npB0 = *(const unsigned*)(kvb + (size_t)nsB.x*(2*DDIM) + 2*l);
      npB1 = *(const unsigned*)(kvb + (size_t)nsB.x*(2*DDIM) + 100 + 2*l);
    }
    uint4 nnsA = nsA, nnsB = nsB;
    if (j+2 < npairs){
      nnsA = spr[b0 + 2*(j+2)];
      nnsB = spr[b0 + 2*(j+2) + 1];
    }

    float relA = __uint_as_float(sA.z);
    float relB = __uint_as_float(sB.z);
    float cAA=0,cBA=0,cAB=0,cBB=0;
    float kA0=0,vA0=0,kA1=0,vA1=0,kB0=0,vB0=0,kB1=0,vB1=0;
    if (act){
      kA0 = bf2f((unsigned short)(pA0 & 0xffff)); vA0 = bf2f((unsigned short)(pA0 >> 16));
      kA1 = bf2f((unsigned short)(pA1 & 0xffff)); vA1 = bf2f((unsigned short)(pA1 >> 16));
      kB0 = bf2f((unsigned short)(pB0 & 0xffff)); vB0 = bf2f((unsigned short)(pB0 >> 16));
      kB1 = bf2f((unsigned short)(pB1 & 0xffff)); vB1 = bf2f((unsigned short)(pB1 >> 16));
      cAA = fast_cos(__fadd_rn(__fmul_rn(relA, wtA), btA));
      cBA = fast_cos(__fadd_rn(__fmul_rn(relA, wtB), btB));
      cAB = fast_cos(__fadd_rn(__fmul_rn(relB, wtA), btA));
      cBB = fast_cos(__fadd_rn(__fmul_rn(relB, wtB), btB));
    }
    float pA_0 = fmaf(q0,kA0, fmaf(qx0,cAA, fmaf(qx1,cBA, fmaf(qx2,mAA, qx3*mBA))));
    float pA_1 = fmaf(q1,kA1, fmaf(qx4,cAA, fmaf(qx5,cBA, fmaf(qx6,mAA, qx7*mBA))));
    float pB_0 = fmaf(q0,kB0, fmaf(qx0,cAB, fmaf(qx1,cBB, fmaf(qx2,mAB, qx3*mBB))));
    float pB_1 = fmaf(q1,kB1, fmaf(qx4,cAB, fmaf(qx5,cBB, fmaf(qx6,mAB, qx7*mBB))));
    #pragma unroll
    for (int m=1; m<64; m<<=1){
      pA_0 += __shfl_xor(pA_0, m);
      pA_1 += __shfl_xor(pA_1, m);
      pB_0 += __shfl_xor(pB_0, m);
      pB_1 += __shfl_xor(pB_1, m);
    }
    float aA0 = __expf(pA_0*INV), aA1 = __expf(pA_1*INV);
    float aB0 = __expf(pB_0*INV), aB1 = __expf(pB_1*INV);
    den0 += aA0 + aB0; den1 += aA1 + aB1;
    nv0 = fmaf(aA0, vA0, nv0); nv0 = fmaf(aB0, vB0, nv0);
    nv1 = fmaf(aA1, vA1, nv1); nv1 = fmaf(aB1, vB1, nv1);
    sb0 = fmaf(aA0, cAA, sb0); sb0 = fmaf(aB0, cAB, sb0);
    sb1 = fmaf(aA0, cBA, sb1); sb1 = fmaf(aB0, cBB, sb1);
    sb2 = fmaf(aA0, mAA, sb2); sb2 = fmaf(aB0, mAB, sb2);
    sb3 = fmaf(aA0, mBA, sb3); sb3 = fmaf(aB0, mBB, sb3);
    sb4 = fmaf(aA1, cAA, sb4); sb4 = fmaf(aB1, cAB, sb4);
    sb5 = fmaf(aA1, cBA, sb5); sb5 = fmaf(aB1, cBB, sb5);
    sb6 = fmaf(aA1, mAA, sb6); sb6 = fmaf(aB1, mAB, sb6);
    sb7 = fmaf(aA1, mBA, sb7); sb7 = fmaf(aB1, mBB, sb7);

    sA = nsA; sB = nsB; nsA = nnsA; nsB = nnsB;
    mAA = nmAA; mBA = nmBA; mAB = nmAB; mBB = nmBB;
    pA0 = npA0; pA1 = npA1; pB0 = npB0; pB1 = npB1;
  }

  if (nE & 1){
    int p = b0 + 2*npairs;
    uint4 eA = spr[p];
    float relA = __uint_as_float(eA.z);
    float cAA=0,cBA=0,mA0=0,mB0=0,kA0=0,vA0=0,kA1=0,vA1=0;
    if (act){
      mA0 = msg[(size_t)eA.y*DDIM + l];  mB0 = msg[(size_t)eA.y*DDIM + 50 + l];
      unsigned tA0 = *(const unsigned*)(kvb + (size_t)eA.x*(2*DDIM) + 2*l);
      unsigned tA1 = *(const unsigned*)(kvb + (size_t)eA.x*(2*DDIM) + 100 + 2*l);
      kA0 = bf2f((unsigned short)(tA0 & 0xffff)); vA0 = bf2f((unsigned short)(tA0 >> 16));
      kA1 = bf2f((unsigned short)(tA1 & 0xffff)); vA1 = bf2f((unsigned short)(tA1 >> 16));
      cAA = fast_cos(__fadd_rn(__fmul_rn(relA, wtA), btA));
      cBA = fast_cos(__fadd_rn(__fmul_rn(relA, wtB), btB));
    }
    float pA_0 = fmaf(q0,kA0, fmaf(qx0,cAA, fmaf(qx1,cBA, fmaf(qx2,mA0, qx3*mB0))));
    float pA_1 = fmaf(q1,kA1, fmaf(qx4,cAA, fmaf(qx5,cBA, fmaf(qx6,mA0, qx7*mB0))));
    #pragma unroll
    for (int m=1; m<64; m<<=1){
      pA_0 += __shfl_xor(pA_0, m);
      pA_1 += __shfl_xor(pA_1, m);
    }
    float aA0 = __expf(pA_0*INV), aA1 = __expf(pA_1*INV);
    den0 += aA0; den1 += aA1;
    nv0 = fmaf(aA0, vA0, nv0);
    nv1 = fmaf(aA1, vA1, nv1);
    sb0 = fmaf(aA0, cAA, sb0); sb1 = fmaf(aA0, cBA, sb1);
    sb2 = fmaf(aA0, mA0, sb2); sb3 = fmaf(aA0, mB0, sb3);
    sb4 = fmaf(aA1, cAA, sb4); sb5 = fmaf(aA1, cBA, sb5);
    sb6 = fmaf(aA1, mA0, sb6); sb7 = fmaf(aA1, mB0, sb7);
  }

  if (act){
    unsigned short* sr = sbarb + (size_t)node*400;
    sr[l]       = f2bf(sb0); sr[50+l]  = f2bf(sb1);
    sr[100+l]   = f2bf(sb2); sr[150+l] = f2bf(sb3);
    sr[200+l]   = f2bf(sb4); sr[250+l] = f2bf(sb5);
    sr[300+l]   = f2bf(sb6); sr[350+l] = f2bf(sb7);
    numvb[(size_t)node*DDIM + l]      = nv0;
    numvb[(size_t)node*DDIM + 50 + l] = nv1;
  }
  if (lane == 0){
    denb[node*2]   = den0;
    denb[node*2+1] = den1;
  }
}

// ---------------- final over nlist: oute = (numv + sbar@We)/den + skip ----------------
__global__ __launch_bounds__(256) void k_final(
    const unsigned short* __restrict__ sbarb, const unsigned short* __restrict__ Wfb,
    const int* __restrict__ srci, const int* __restrict__ dsti,
    const float* __restrict__ numvb, const float* __restrict__ denb,
    const float* __restrict__ ssb, float* __restrict__ oute)
{
  const int tid = threadIdx.x;
  const int lane = tid & 63;
  const int w = tid >> 6;
  const int i0 = blockIdx.x*64;
  const int arow = w*16 + (lane & 15);
  const int koff = (lane >> 4) << 3;

  int idx = i0 + arow;
  int idxc = (idx < NL) ? idx : (NL-1);
  int node = (idxc < NB) ? srci[idxc] : dsti[idxc - NB];
  const unsigned short* srow = sbarb + (size_t)node*400;

  f32x4 acc[7];
  #pragma unroll
  for (int nt=0; nt<7; ++nt) acc[nt] = (f32x4){0,0,0,0};

  #pragma unroll
  for (int kt=0; kt<13; ++kt){
    const int k0 = kt*32 + koff;
    short8 a;
    if (k0 + 7 < 2*KATTR){
      a = *(const short8*)(srow + k0);
    } else {
      #pragma unroll
      for (int j=0;j<8;++j) a[j] = 0;
    }
    const short8* wb = (const short8*)Wfb + (size_t)(kt*7)*64 + lane;
    #pragma unroll
    for (int nt=0; nt<7; ++nt){
      short8 b = wb[(size_t)nt*64];
      acc[nt] = __builtin_amdgcn_mfma_f32_16x16x32_bf16(a, b, acc[nt], 0, 0, 0);
    }
  }

  const int colb = lane & 15;
  const int rbase = w*16 + ((lane >> 4) << 2);
  int nd[4]; bool on[4];
  #pragma unroll
  for (int r=0; r<4; ++r){
    int ii = i0 + rbase + r;
    on[r] = ii < NL;
    int iic = on[r] ? ii : (NL-1);
    nd[r] = (iic < NB) ? srci[iic] : dsti[iic - NB];
  }
  #pragma unroll
  for (int nt=0; nt<7; ++nt){
    int col = nt*16 + colb;
    if (col >= DDIM) continue;
    int h = col >= 50 ? 1 : 0;
    #pragma unroll
    for (int r=0; r<4; ++r){
      if (on[r]){
        float den = denb[nd[r]*2 + h];
        float nv  = numvb[(size_t)nd[r]*DDIM + col];
        oute[(size_t)nd[r]*DDIM + col] =
          (nv + acc[nt][r]) / (den + 1e-16f) + ssb[(size_t)nd[r]*DDIM + col];
      }
    }
  }
}

// ---------------- predictor via MFMA ----------------
__global__ __launch_bounds__(256) void k_pred(
    const float* __restrict__ oute, const int* __restrict__ srci, const int* __restrict__ dsti,
    const unsigned short* __restrict__ Wnb,
    const float* __restrict__ bps, const float* __restrict__ bpd,
    const float* __restrict__ bpf, float* __restrict__ outp)
{
  __shared__ float hl[64][104];
  const int tid = threadIdx.x;
  const int lane = tid & 63;
  const int w = tid >> 6;
  const int bb0 = blockIdx.x*64;
  const int arow = w*16 + (lane & 15);
  const int koff = (lane >> 4) << 3;

  int b = bb0 + arow;
  int bc = (b < NB) ? b : (NB-1);
  const float* srow = oute + (size_t)srci[bc]*DDIM;
  const float* drow = oute + (size_t)dsti[bc]*DDIM;

  f32x4 acc[7];
  #pragma unroll
  for (int nt=0; nt<7; ++nt) acc[nt] = (f32x4){0,0,0,0};

  #pragma unroll
  for (int kt=0; kt<4; ++kt){
    const int k0 = kt*32 + koff;
    short8 aS, aD;
    if (k0 + 7 < DDIM){
      float4 s0 = *(const float4*)(srow + k0);
      float4 s1 = *(const float4*)(srow + k0 + 4);
      float4 d0 = *(const float4*)(drow + k0);
      float4 d1 = *(const float4*)(drow + k0 + 4);
      aS[0]=(short)f2bf(s0.x); aS[1]=(short)f2bf(s0.y); aS[2]=(short)f2bf(s0.z); aS[3]=(short)f2bf(s0.w);
      aS[4]=(short)f2bf(s1.x); aS[5]=(short)f2bf(s1.y); aS[6]=(short)f2bf(s1.z); aS[7]=(short)f2bf(s1.w);
      aD[0]=(short)f2bf(d0.x); aD[1]=(short)f2bf(d0.y); aD[2]=(short)f2bf(d0.z); aD[3]=(short)f2bf(d0.w);
      aD[4]=(short)f2bf(d1.x); aD[5]=(short)f2bf(d1.y); aD[6]=(short)f2bf(d1.z); aD[7]=(short)f2bf(d1.w);
    } else if (k0 >= DDIM){
      #pragma unroll
      for (int j=0;j<8;++j){ aS[j]=0; aD[j]=0; }
    } else {
      float4 s0 = *(const float4*)(srow + 96);
      float4 d0 = *(const float4*)(drow + 96);
      aS[0]=(short)f2bf(s0.x); aS[1]=(short)f2bf(s0.y); aS[2]=(short)f2bf(s0.z); aS[3]=(short)f2bf(s0.w);
      aS[4]=0; aS[5]=0; aS[6]=0; aS[7]=0;
      aD[0]=(short)f2bf(d0.x); aD[1]=(short)f2bf(d0.y); aD[2]=(short)f2bf(d0.z); aD[3]=(short)f2bf(d0.w);
      aD[4]=0; aD[5]=0; aD[6]=0; aD[7]=0;
    }
    const short8* wps = (const short8*)Wnb + (size_t)((4*4 + kt)*7)*64 + lane;
    const short8* wpd = (const short8*)Wnb + (size_t)((5*4 + kt)*7)*64 + lane;
    #pragma unroll
    for (int nt=0; nt<7; ++nt){
      acc[nt] = __builtin_amdgcn_mfma_f32_16x16x32_bf16(aS, wps[(size_t)nt*64], acc[nt], 0, 0, 0);
      acc[nt] = __builtin_amdgcn_mfma_f32_16x16x32_bf16(aD, wpd[(size_t)nt*64], acc[nt], 0, 0, 0);
    }
  }

  const int colb = lane & 15;
  const int rbase = w*16 + ((lane >> 4) << 2);
  #pragma unroll
  for (int nt=0; nt<7; ++nt){
    int col = nt*16 + colb;
    if (col >= DDIM) continue;
    float bbias = bps[col] + bpd[col];
    #pragma unroll
    for (int r=0; r<4; ++r)
      hl[rbase + r][col] = fmaxf(acc[nt][r] + bbias, 0.f);
  }
  __syncthreads();

  f32x4 ac2[7];
  #pragma unroll
  for (int nt=0; nt<7; ++nt) ac2[nt] = (f32x4){0,0,0,0};

  #pragma unroll
  for (int kt=0; kt<4; ++kt){
    const int k0 = kt*32 + koff;
    short8 a;
    if (k0 + 7 < DDIM){
      float4 h0 = *(const float4*)(&hl[arow][k0]);
      float4 h1 = *(const float4*)(&hl[arow][k0 + 4]);
      a[0]=(short)f2bf(h0.x); a[1]=(short)f2bf(h0.y); a[2]=(short)f2bf(h0.z); a[3]=(short)f2bf(h0.w);
      a[4]=(short)f2bf(h1.x); a[5]=(short)f2bf(h1.y); a[6]=(short)f2bf(h1.z); a[7]=(short)f2bf(h1.w);
    } else if (k0 >= DDIM){
      #pragma unroll
      for (int j=0;j<8;++j) a[j] = 0;
    } else {
      float4 h0 = *(const float4*)(&hl[arow][96]);
      a[0]=(short)f2bf(h0.x); a[1]=(short)f2bf(h0.y); a[2]=(short)f2bf(h0.z); a[3]=(short)f2bf(h0.w);
      a[4]=0; a[5]=0; a[6]=0; a[7]=0;
    }
    const short8* wpf = (const short8*)Wnb + (size_t)((6*4 + kt)*7)*64 + lane;
    #pragma unroll
    for (int nt=0; nt<7; ++nt)
      ac2[nt] = __builtin_amdgcn_mfma_f32_16x16x32_bf16(a, wpf[(size_t)nt*64], ac2[nt], 0, 0, 0);
  }

  #pragma unroll
  for (int nt=0; nt<7; ++nt){
    int col = nt*16 + colb;
    if (col >= DDIM) continue;
    float bb = bpf[col];
    #pragma unroll
    for (int r=0; r<4; ++r){
      int bo = bb0 + rbase + r;
      if (bo < NB) outp[(size_t)bo*DDIM + col] = ac2[nt][r] + bb;
    }
  }
}

extern "C" void kernel_launch(void* const* d_in, const int* in_sizes, int n_in,
                              void* d_out, int out_size, void* d_ws, size_t ws_size,
                              hipStream_t stream)
{
  const float* mem   = (const float*)d_in[0];
  const int*   lastu = (const int*)  d_in[1];
  const int*   nid   = (const int*)  d_in[2];
  const int*   ei    = (const int*)  d_in[3];
  const int*   tt    = (const int*)  d_in[4];
  const float* msg   = (const float*)d_in[5];
  const int*   srci  = (const int*)  d_in[6];
  const int*   dsti  = (const int*)  d_in[7];
  const float* wtime = (const float*)d_in[8];
  const float* btime = (const float*)d_in[9];
  const float* Wq = (const float*)d_in[10]; const float* bq = (const float*)d_in[11];
  const float* Wk = (const float*)d_in[12]; const float* bk = (const float*)d_in[13];
  const float* Wv = (const float*)d_in[14]; const float* bv = (const float*)d_in[15];
  const float* We = (const float*)d_in[16];
  const float* Ws = (const float*)d_in[17]; const float* bs = (const float*)d_in[18];
  const float* Wps= (const float*)d_in[19]; const float* bps= (const float*)d_in[20];
  const float* Wpd= (const float*)d_in[21]; const float* bpd= (const float*)d_in[22];
  const float* Wpf= (const float*)d_in[23]; const float* bpf= (const float*)d_in[24];

  char* wsp = (char*)d_ws;
  auto alloc = [&](size_t bytes)->void*{
    void* p = (void*)wsp;
    wsp += (bytes + 255) & ~(size_t)255;
    return p;
  };
  float* qs   = (float*)alloc((size_t)N_SUBN*DDIM*4);
  unsigned short* kvb  = (unsigned short*)alloc((size_t)N_SUBN*DDIM*2*2);
  float* ssb  = (float*)alloc((size_t)N_SUBN*DDIM*4);
  float* oute = (float*)alloc((size_t)N_SUBN*DDIM*4);
  unsigned short* qexb = (unsigned short*)alloc((size_t)N_SUBN*400*2);
  unsigned short* sbarb= (unsigned short*)alloc((size_t)N_SUBN*400*2);
  float* numvb= (float*)alloc((size_t)N_SUBN*DDIM*4);
  float* denb = (float*)alloc((size_t)N_SUBN*2*4);
  int* cnt    = (int*)alloc((size_t)N_SUBN*4);
  int* mark   = (int*)alloc((size_t)N_SUBN*4);
  int* mark2  = (int*)alloc((size_t)N_SUBN*4);
  int* rowptr = (int*)alloc((size_t)(N_SUBN+1)*4);
  int* ofs    = (int*)alloc((size_t)N_SUBN*4);
  int* bsum   = (int*)alloc((size_t)NCHUNK*4);
  uint4* spr  = (uint4*)alloc((size_t)NE*16);
  int* lusub  = (int*)alloc((size_t)N_SUBN*4);
  unsigned short* Wnb  = (unsigned short*)alloc((size_t)7*28*64*8*2);
  unsigned short* Wqxb = (unsigned short*)alloc((size_t)4*25*64*8*2);
  unsigned short* Wfb  = (unsigned short*)alloc((size_t)13*7*64*8*2);

  k_misc<<<(N_SUBN+255)/256, 256, 0, stream>>>(lastu, nid, cnt, mark, mark2, lusub, We,
                                               Wq, Wk, Wv, Ws, Wps, Wpd, Wpf,
                                               Wnb, Wqxb, Wfb);
  k_mark<<<(NB+255)/256, 256, 0, stream>>>(srci, dsti, mark);
  k_hist<<<(NE+255)/256, 256, 0, stream>>>(ei, mark, cnt, mark2);
  k_bsum<<<NCHUNK, 256, 0, stream>>>(cnt, bsum);
  k_off<<<NCHUNK, 1024, 0, stream>>>(cnt, bsum, rowptr, ofs);
  k_perm<<<(NE+255)/256, 256, 0, stream>>>(ei, tt, lusub, mark, ofs, spr);

  k_nodeKV<<<(N_SUBN+63)/64, 256, 0, stream>>>(mem, nid, mark2, Wnb, bk, bv, kvb);
  k_nodeQS<<<(NL+63)/64, 256, 0, stream>>>(mem, nid, srci, dsti, Wnb, bq, bs, qs, ssb);
  k_qex<<<(NL+63)/64, 256, 0, stream>>>(qs, srci, dsti, Wqxb, qexb);

  k_agg<<<NL/4, 256, 0, stream>>>(rowptr, spr, srci, dsti, msg, qs,
                                  qexb, kvb, wtime, btime,
                                  sbarb, numvb, denb);

  k_final<<<(NL+63)/64, 256, 0, stream>>>(sbarb, Wfb, srci, dsti, numvb, denb, ssb, oute);

  k_pred<<<(NB+63)/64, 256, 0, stream>>>(oute, srci, dsti, Wnb, bps, bpd, bpf,
                                         (float*)d_out);
}